// Round 9
// baseline (381.646 us; speedup 1.0000x reference)
//
#include <hip/hip_runtime.h>
#include <stdint.h>

// Problem constants (B=64, P=24564, 21 classes)
#define NC 21
#define BATCH 64
#define PRI 24564
#define NROWS (BATCH * PRI)   // 1,572,096
#define SLABS 32              // k_sl1 slabs per batch row
#define SLABR 768             // rows per slab (last slab: 756 valid)
#define GBLK (BATCH * SLABS)  // 2048 k_sl1 blocks
#define NBJ 96                // k_ce blocks per batch (256 rows each; last has 244)
#define NB (BATCH * NBJ)      // 6144 k_ce blocks
#define BTHR 1024             // k_batch threads
#define BITER 24              // ceil(PRI / BTHR)
#define NSTRIPE (BITER * 16)  // 384 64-row stripes per batch (stripe order == index order)

__device__ __forceinline__ float sl1f(float p, float t) {
    float d = fabsf(p - t);
    return d < 1.0f ? 0.5f * d * d : d - 0.5f;
}

// monotonic float -> uint key map (order-preserving)
__device__ __forceinline__ unsigned int f2k(float v) {
    unsigned int u = __float_as_uint(v);
    return (u & 0x80000000u) ? ~u : (u | 0x80000000u);
}

// 256-thread block reduce (4 waves of 64). Valid on tid==0 only.
__device__ __forceinline__ double blockReduce(double v, double* sred) {
    #pragma unroll
    for (int off = 32; off > 0; off >>= 1)
        v += __shfl_down(v, off, 64);
    const int wid = threadIdx.x >> 6, lane = threadIdx.x & 63;
    __syncthreads();
    if (lane == 0) sred[wid] = v;
    __syncthreads();
    double r = 0.0;
    if (threadIdx.x == 0) r = sred[0] + sred[1] + sred[2] + sred[3];
    return r;
}

// 1024-thread block reduce (16 waves of 64). Valid on tid==0 only.
__device__ __forceinline__ double bred16(double v, double* sred) {
    #pragma unroll
    for (int off = 32; off > 0; off >>= 1)
        v += __shfl_down(v, off, 64);
    const int wid = threadIdx.x >> 6, lane = threadIdx.x & 63;
    __syncthreads();
    if (lane == 0) sred[wid] = v;
    __syncthreads();
    double r = 0.0;
    if (threadIdx.x == 0) {
        #pragma unroll
        for (int i = 0; i < 16; ++i) r += sred[i];
    }
    __syncthreads();   // allow sred reuse by caller
    return r;
}

// k_ce v2: isolated conf stream, LDS-staged via FLAT float4 loads.
// r8 found harness fill kernels stream 528 MB at 6.9 TB/s (8 VGPR, 10% occ) —
// the chip streams fine; our 84-B-strided dwordx4 reads (~64 line-txns/load)
// ran at 1.5 TB/s. Stage each block's contiguous 21.5 KB conf slice with
// float4 flat loads (16 lines/wave-load, fill-equivalent), then CE from LDS
// (stride-21 dword reads: gcd(21,32)=1 -> 2-way aliasing = free; gg gather
// becomes LDS read). Alignment: (b*24564+j*256)*84 B is 16B-aligned; vrows*21
// divisible by 4 for vrows in {256, 244}. Two LDS passes (max, sum) keep
// per-thread state ~12 VGPR — no spill at (256,4).
__global__ __launch_bounds__(256, 4) void k_ce(
    const float* __restrict__ conf_data, const int* __restrict__ conf_t,
    float* __restrict__ wsf /* = (float*)ws_ch */, double* __restrict__ partPN)
{
    __shared__ float sconf[256 * NC];   // 21504 B
    __shared__ double sred[4];
    const int tid = threadIdx.x;
    const int b = blockIdx.y, j = blockIdx.x;
    const int r0 = j * 256;
    const int vrows = (PRI - r0 < 256) ? (PRI - r0) : 256;
    const unsigned rb = (unsigned)b * PRI;

    // stage conf slice: vrows*21 floats as float4 stream (fully coalesced)
    {
        const float4* src4 = (const float4*)(conf_data + (size_t)(rb + r0) * NC);
        const int nf4 = (vrows * NC) >> 2;   // exact: vrows*21 % 4 == 0 for 256/244
        float4* dst4 = (float4*)sconf;
        for (int idx = tid; idx < nf4; idx += 256) dst4[idx] = src4[idx];
    }
    const bool vld = tid < vrows;
    const int p = vld ? (r0 + tid) : (PRI - 1);
    const int ct = conf_t[rb + p];          // independent load, overlaps staging
    __syncthreads();

    // CE from LDS: pass 1 max, pass 2 sum (tiny register footprint)
    const int base = tid * NC;              // tid>=vrows reads in-bounds garbage; gated below
    float m = sconf[base];
    #pragma unroll
    for (int q = 1; q < NC; ++q) m = fmaxf(m, sconf[base + q]);
    float sum = 0.f;
    #pragma unroll
    for (int q = 0; q < NC; ++q) sum += __expf(sconf[base + q] - m);
    const float gg = sconf[base + ct];
    const float ce = m + __logf(sum) - gg;

    const bool pos = ct > 0;
    if (vld) wsf[2u * (rb + p)] = ce;
    const int myp = (vld && pos) ? 1 : 0;
    const int myn = (vld && !pos && f2k(ce) != 0x80000000u) ? 1 : 0;

    const int sb = b * NBJ + j;
    double v;
    v = blockReduce((double)myp, sred);
    if (tid == 0) partPN[0 * NB + sb] = v;   // pos count
    v = blockReduce((double)myn, sred);
    if (tid == 0) partPN[1 * NB + sb] = v;   // nonzero-key negative count
}

// B: smooth-L1 partials + has_lp CE/posbit -> ws_ch.y; partL[0..2].
// (r8-verified body, unchanged.)
__global__ __launch_bounds__(256, 4) void k_sl1(
    const float* __restrict__ loc_data, const float* __restrict__ has_lp_data,
    const float* __restrict__ size_lp_data, const float* __restrict__ offset_data,
    const float* __restrict__ loc_t, const int* __restrict__ conf_t,
    const int* __restrict__ has_lp_t, const float* __restrict__ size_lp_t,
    const float* __restrict__ offset_t,
    float* __restrict__ wsf /* = (float*)ws_ch */, double* __restrict__ partL)
{
    __shared__ double sred[4];
    const int tid = threadIdx.x;
    const int b = blockIdx.x >> 5, s = blockIdx.x & 31;

    int pr[3]; bool vld[3];
    #pragma unroll
    for (int i = 0; i < 3; ++i) {
        int p = s * SLABR + i * 256 + tid;
        vld[i] = p < PRI;
        pr[i] = vld[i] ? p : PRI - 1;
    }
    const unsigned rb = (unsigned)b * PRI;

    int ct[3], hl[3]; float4 lp[3], lt[3]; float2 sp2[3], st2[3], op2[3], ot2[3], hh[3];
    #pragma unroll
    for (int i = 0; i < 3; ++i) {
        const unsigned r = rb + pr[i];
        ct[i] = conf_t[r];
        hl[i] = has_lp_t[r];
        lp[i] = ((const float4*)loc_data)[r];
        lt[i] = ((const float4*)loc_t)[r];
        sp2[i] = ((const float2*)size_lp_data)[r];
        st2[i] = ((const float2*)size_lp_t)[r];
        op2[i] = ((const float2*)offset_data)[r];
        ot2[i] = ((const float2*)offset_t)[r];
        hh[i] = ((const float2*)has_lp_data)[r];
    }
    double aL = 0.0, aS = 0.0, aO = 0.0;
    #pragma unroll
    for (int i = 0; i < 3; ++i) {
        const bool pos = ct[i] > 0;
        float ll = sl1f(lp[i].x, lt[i].x) + sl1f(lp[i].y, lt[i].y)
                 + sl1f(lp[i].z, lt[i].z) + sl1f(lp[i].w, lt[i].w);
        float ls = sl1f(sp2[i].x, st2[i].x) + sl1f(sp2[i].y, st2[i].y);
        float lo = sl1f(op2[i].x, ot2[i].x) + sl1f(op2[i].y, ot2[i].y);
        const float pf = (vld[i] && pos) ? 1.f : 0.f;
        const float hf = (hl[i] != 0) ? 1.f : 0.f;
        aL += (double)(pf * ll);
        aS += (double)(pf * hf * ls);
        aO += (double)(pf * hf * lo);
        float hm = fmaxf(hh[i].x, hh[i].y);
        float hs = __expf(hh[i].x - hm) + __expf(hh[i].y - hm);
        float hlce = fmaxf(hm + __logf(hs) - (hl[i] != 0 ? hh[i].y : hh[i].x), 0.0f);
        unsigned hb = __float_as_uint(hlce) | (pos ? 0x80000000u : 0u);
        if (vld[i]) wsf[2u * (rb + pr[i]) + 1u] = __uint_as_float(hb);
    }
    double v;
    v = blockReduce(aL, sred); if (tid == 0) partL[0 * GBLK + blockIdx.x] = v;
    v = blockReduce(aS, sred); if (tid == 0) partL[1 * GBLK + blockIdx.x] = v;
    v = blockReduce(aO, sred); if (tid == 0) partL[2 * GBLK + blockIdx.x] = v;
}

// Per-batch selection pipeline (r8-verified structure; K/M from 96-slab partPN).
__global__ __launch_bounds__(BTHR) void k_batch(
    const float2* __restrict__ ws_ch, const double* __restrict__ partPN,
    double* __restrict__ lossCH)
{
    const int b = blockIdx.x, tid = threadIdx.x;
    const int lane = tid & 63, wid = tid >> 6;
    __shared__ int shist[4096];
    __shared__ int sct[BTHR];
    __shared__ int sCnt[NSTRIPE];
    __shared__ double sTC[NSTRIPE], sTH[NSTRIPE];
    __shared__ double sred[16];
    __shared__ double s_np, s_M;
    __shared__ unsigned s_dig;
    __shared__ int s_rem;
    __shared__ int s_st, s_loc;

    const float2* row = ws_ch + (unsigned)b * PRI;

    // ---- K and M from per-slab counts written by k_ce (96 slabs) ----
    {
        double npv = bred16((tid < NBJ) ? partPN[0 * NB + b * NBJ + tid] : 0.0, sred);
        if (tid == 0) s_np = npv;
        double mmv = bred16((tid < NBJ) ? partPN[1 * NB + b * NBJ + tid] : 0.0, sred);
        if (tid == 0) s_M = mmv;
    }
    __syncthreads();
    int K = 3 * (int)(s_np + 0.5);
    if (K > PRI - 1) K = PRI - 1;
    const int M = (int)(s_M + 0.5);

    if (K <= 0) {
        if (tid == 0) { lossCH[b] = 0.0; lossCH[64 + b] = 0.0; }
        return;
    }

    unsigned T; int need;
    if (K > M) {
        T = 0x80000000u; need = K - M;   // threshold sits in zero-key population
    } else {
        // ---- rare path: radix threshold pick entirely in LDS ----
        for (int k = tid; k < 4096; k += BTHR) shist[k] = 0;
        __syncthreads();
        for (int i = 0; i < BITER; ++i) {
            const int p = i * BTHR + tid;
            if (p < PRI) {
                float2 ch = row[p];
                unsigned hb = __float_as_uint(ch.y);
                if (!(hb >> 31)) {
                    unsigned key = f2k(ch.x);
                    if (key != 0x80000000u) atomicAdd(&shist[key >> 20], 1);
                }
            }
        }
        __syncthreads();
        {
            int h4[4]; int ctn = 0;
            #pragma unroll
            for (int j = 0; j < 4; ++j) { h4[j] = shist[tid * 4 + j]; ctn += h4[j]; }
            sct[tid] = ctn;
            __syncthreads();
            #pragma unroll
            for (int off = 1; off < BTHR; off <<= 1) {   // suffix sum
                int v = (tid + off < BTHR) ? sct[tid + off] : 0;
                __syncthreads();
                sct[tid] += v;
                __syncthreads();
            }
            const int Sa = (tid < BTHR - 1) ? sct[tid + 1] : 0;
            int cum = Sa;
            #pragma unroll
            for (int j = 3; j >= 0; --j) {
                int c2 = cum + h4[j];
                if (c2 >= K && cum < K) { s_dig = (unsigned)(tid * 4 + j); s_rem = K - cum; }
                cum = c2;
            }
            __syncthreads();
        }
        unsigned pref = s_dig; int rem = s_rem;
        __syncthreads();

        // refine 1: bits 19..10 where key>>20 == pref
        if (tid < 1024) shist[tid] = 0;
        __syncthreads();
        for (int i = 0; i < BITER; ++i) {
            const int p = i * BTHR + tid;
            if (p < PRI) {
                float2 ch = row[p];
                unsigned hb = __float_as_uint(ch.y);
                if (!(hb >> 31)) {
                    unsigned key = f2k(ch.x);
                    if (key != 0x80000000u && (key >> 20) == pref)
                        atomicAdd(&shist[(key >> 10) & 1023], 1);
                }
            }
        }
        __syncthreads();
        {
            const int hb1 = shist[tid];
            sct[tid] = hb1;
            __syncthreads();
            #pragma unroll
            for (int off = 1; off < BTHR; off <<= 1) {
                int v = (tid + off < BTHR) ? sct[tid + off] : 0;
                __syncthreads();
                sct[tid] += v;
                __syncthreads();
            }
            const int Sa = (tid < BTHR - 1) ? sct[tid + 1] : 0;
            if (Sa + hb1 >= rem && Sa < rem) { s_dig = (unsigned)tid; s_rem = rem - Sa; }
            __syncthreads();
        }
        pref = (pref << 10) | s_dig; rem = s_rem;
        __syncthreads();

        // refine 2: low 10 bits where key>>10 == pref
        if (tid < 1024) shist[tid] = 0;
        __syncthreads();
        for (int i = 0; i < BITER; ++i) {
            const int p = i * BTHR + tid;
            if (p < PRI) {
                float2 ch = row[p];
                unsigned hb = __float_as_uint(ch.y);
                if (!(hb >> 31)) {
                    unsigned key = f2k(ch.x);
                    if (key != 0x80000000u && (key >> 10) == pref)
                        atomicAdd(&shist[key & 1023], 1);
                }
            }
        }
        __syncthreads();
        {
            const int hb1 = shist[tid];
            sct[tid] = hb1;
            __syncthreads();
            #pragma unroll
            for (int off = 1; off < BTHR; off <<= 1) {
                int v = (tid + off < BTHR) ? sct[tid + off] : 0;
                __syncthreads();
                sct[tid] += v;
                __syncthreads();
            }
            const int Sa = (tid < BTHR - 1) ? sct[tid + 1] : 0;
            if (Sa + hb1 >= rem && Sa < rem) { s_dig = (unsigned)tid; s_rem = rem - Sa; }
            __syncthreads();
        }
        T = (pref << 10) | s_dig; need = s_rem;
        __syncthreads();
    }

    // ---- stats scan ----
    double aC = 0.0, aH = 0.0;
    for (int i = 0; i < BITER; ++i) {
        const int p = i * BTHR + tid;
        const bool valid = p < PRI;
        float2 ch = valid ? row[p] : make_float2(0.f, 0.f);
        const unsigned hb = __float_as_uint(ch.y);
        const bool pos = (hb >> 31) != 0;
        const unsigned key = pos ? 0x80000000u : f2k(ch.x);
        const float hlv = __uint_as_float(hb & 0x7fffffffu);
        if (valid && (pos || key > T)) { aC += (double)ch.x; aH += (double)hlv; }
        const bool eq = valid && (key == T);
        const unsigned long long msk = __ballot(eq);
        const unsigned long long mneg = __ballot(eq && !pos);
        double tc = 0.0, th = 0.0;
        if (mneg) {   // wave-uniform: only reduce when a tie-negative exists
            tc = (eq && !pos) ? (double)ch.x : 0.0;
            th = (eq && !pos) ? (double)hlv : 0.0;
            #pragma unroll
            for (int off = 32; off > 0; off >>= 1) {
                tc += __shfl_down(tc, off, 64);
                th += __shfl_down(th, off, 64);
            }
        }
        if (lane == 0) {
            sCnt[i * 16 + wid] = (int)__popcll(msk);
            sTC[i * 16 + wid] = tc;
            sTH[i * 16 + wid] = th;
        }
    }
    const double aCt = bred16(aC, sred);   // syncs cover sCnt/sTC/sTH
    const double aHt = bred16(aH, sred);

    // ---- tail: locate cutoff stripe, accumulate tie-neg sums before it ----
    double accC = 0.0, accH = 0.0;
    if (tid == 0) {
        int st = -1, loc = 0, cum = 0;
        if (need > 0) {
            for (int s2 = 0; s2 < NSTRIPE; ++s2) {
                const int c = sCnt[s2];
                if (cum + c >= need) { st = s2; loc = need - cum; break; }
                cum += c;
                accC += sTC[s2]; accH += sTH[s2];
            }
        }
        s_st = st; s_loc = loc;
    }
    __syncthreads();
    const int st = s_st, loc = s_loc;

    double pC = 0.0, pH = 0.0;
    if (wid == 0 && st >= 0) {   // wave 0 resolves the partial stripe
        const int base = (st >> 4) * BTHR + (st & 15) * 64;
        const int p = base + lane;
        const bool valid = p < PRI;
        float2 ch = valid ? row[p] : make_float2(0.f, 0.f);
        const unsigned hb = __float_as_uint(ch.y);
        const bool pos = (hb >> 31) != 0;
        const unsigned key = pos ? 0x80000000u : f2k(ch.x);
        const float hlv = __uint_as_float(hb & 0x7fffffffu);
        const bool eq = valid && (key == T);
        const unsigned long long msk = __ballot(eq);
        const int rank = (int)__popcll(msk & ((1ull << lane) - 1ull)) + 1;
        int sel = (eq && rank == loc) ? lane : 64;
        #pragma unroll
        for (int off = 32; off > 0; off >>= 1) {
            int o = __shfl_xor(sel, off, 64);
            sel = (o < sel) ? o : sel;
        }
        const bool take = eq && !pos && (lane <= sel);
        pC = take ? (double)ch.x : 0.0;
        pH = take ? (double)hlv : 0.0;
        #pragma unroll
        for (int off = 32; off > 0; off >>= 1) {
            pC += __shfl_down(pC, off, 64);
            pH += __shfl_down(pH, off, 64);
        }
    }
    if (tid == 0) {
        lossCH[b] = aCt + accC + pC;
        lossCH[64 + b] = aHt + accH + pH;
    }
}

// Sum partials, divide by N, emit 5 outputs.
__global__ __launch_bounds__(256) void k_final(
    const double* __restrict__ partL, const double* __restrict__ partPN,
    const double* __restrict__ lossCH, float* __restrict__ out)
{
    __shared__ double sred[4];
    const int tid = threadIdx.x;
    double s[3];
    #pragma unroll
    for (int k = 0; k < 3; ++k) {
        double a = 0.0;
        for (int t = tid; t < GBLK; t += 256) a += partL[k * GBLK + t];
        s[k] = blockReduce(a, sred);
    }
    double a = 0.0;
    for (int t = tid; t < NB; t += 256) a += partPN[t];
    double n = blockReduce(a, sred);
    double lc = (tid < BATCH) ? lossCH[tid] : 0.0;
    lc = blockReduce(lc, sred);
    double lh = (tid < BATCH) ? lossCH[64 + tid] : 0.0;
    lh = blockReduce(lh, sred);
    if (tid == 0) {
        out[0] = (float)(s[0] / n);   // loss_l
        out[1] = (float)(lc / n);     // loss_c
        out[2] = (float)(s[1] / n);   // loss_size_lp
        out[3] = (float)(s[2] / n);   // loss_offset
        out[4] = (float)(lh / n);     // loss_has_lp
    }
}

extern "C" void kernel_launch(void* const* d_in, const int* in_sizes, int n_in,
                              void* d_out, int out_size, void* d_ws, size_t ws_size,
                              hipStream_t stream)
{
    const float* loc_data     = (const float*)d_in[0];
    const float* conf_data    = (const float*)d_in[1];
    const float* has_lp_data  = (const float*)d_in[2];
    const float* size_lp_data = (const float*)d_in[3];
    const float* offset_data  = (const float*)d_in[4];
    const float* loc_t        = (const float*)d_in[5];
    const int*   conf_t       = (const int*)d_in[6];
    const int*   has_lp_t     = (const int*)d_in[7];
    const float* size_lp_t    = (const float*)d_in[8];
    const float* offset_t     = (const float*)d_in[9];
    float* out = (float*)d_out;

    char* ws = (char*)d_ws;
    double* partL    = (double*)(ws + 16384);    // 3*2048 doubles (48 KB) — fully rewritten
    double* partPN   = (double*)(ws + 65536);    // 2*6144 doubles (96 KB) — fully rewritten
    double* lossCH   = (double*)(ws + 262144);   // 128 doubles — fully rewritten
    float2* ws_ch    = (float2*)(ws + 1704960);  // NROWS float2 (~12.6 MB) — fully rewritten

    // No memsets: every workspace word consumed is written unconditionally
    // by an earlier kernel in the same graph.
    k_ce<<<dim3(NBJ, BATCH), 256, 0, stream>>>(conf_data, conf_t, (float*)ws_ch, partPN);
    k_sl1<<<GBLK, 256, 0, stream>>>(loc_data, has_lp_data, size_lp_data, offset_data,
                                    loc_t, conf_t, has_lp_t, size_lp_t, offset_t,
                                    (float*)ws_ch, partL);
    k_batch<<<BATCH, BTHR, 0, stream>>>(ws_ch, partPN, lossCH);
    k_final<<<1, 256, 0, stream>>>(partL, partPN, lossCH, out);
}

// Round 10
// 327.842 us; speedup vs baseline: 1.1641x; 1.1641x over previous
//
#include <hip/hip_runtime.h>
#include <stdint.h>

// Problem constants (B=64, P=24564, 21 classes)
#define NC 21
#define BATCH 64
#define PRI 24564
#define SLABS 32              // slabs per batch row
#define SLABR 768             // rows per slab (last slab: 756 valid)
#define GBLK (BATCH * SLABS)  // 2048 wide-kernel blocks
#define SENT 0xFFFFFFFFu

// float4 with 4-byte alignment (conf rows are 84B-strided, only dword-aligned)
typedef float f4a4 __attribute__((ext_vector_type(4), aligned(4)));

__device__ __forceinline__ float sl1f(float p, float t) {
    float d = fabsf(p - t);
    return d < 1.0f ? 0.5f * d * d : d - 0.5f;
}

// monotonic float -> uint key map (order-preserving)
__device__ __forceinline__ unsigned int f2k(float v) {
    unsigned int u = __float_as_uint(v);
    return (u & 0x80000000u) ? ~u : (u | 0x80000000u);
}

// selection key from packed (ce, hlce|posbit); pos -> f2k(0.0) = 0x80000000
__device__ __forceinline__ unsigned int chkey(float2 ch) {
    unsigned hb = __float_as_uint(ch.y);
    return (hb & 0x80000000u) ? 0x80000000u : f2k(ch.x);
}

// 256-thread block reduce (4 waves of 64). Valid on tid==0 only.
__device__ __forceinline__ double blockReduce(double v, double* sred) {
    #pragma unroll
    for (int off = 32; off > 0; off >>= 1)
        v += __shfl_down(v, off, 64);
    const int wid = threadIdx.x >> 6, lane = threadIdx.x & 63;
    __syncthreads();
    if (lane == 0) sred[wid] = v;
    __syncthreads();
    double r = 0.0;
    if (threadIdx.x == 0) r = sred[0] + sred[1] + sred[2] + sred[3];
    return r;
}

// A: 21-class conf CE -> ws_ch.x; pos / nonzero-key-neg counts (plain stores).
// r8-verified register version (r9's LDS staging was neutral-to-negative).
__global__ __launch_bounds__(256, 4) void k_ce(
    const float* __restrict__ conf_data, const int* __restrict__ conf_t,
    float* __restrict__ wsf /* = (float*)ws_ch */, double* __restrict__ partPN)
{
    __shared__ double sred[4];
    const int tid = threadIdx.x;
    const int b = blockIdx.x >> 5, s = blockIdx.x & 31;

    int pr[3]; bool vld[3];
    #pragma unroll
    for (int i = 0; i < 3; ++i) {
        int p = s * SLABR + i * 256 + tid;
        vld[i] = p < PRI;
        pr[i] = vld[i] ? p : PRI - 1;   // clamp: loads unconditional, safe
    }
    const unsigned rb = (unsigned)b * PRI;

    int ct[3];
    #pragma unroll
    for (int i = 0; i < 3; ++i) ct[i] = conf_t[rb + pr[i]];
    f4a4 cw[3][5]; float c20[3], gg[3];
    #pragma unroll
    for (int i = 0; i < 3; ++i) {
        const float* crow = conf_data + (long)(rb + pr[i]) * NC;
        #pragma unroll
        for (int j = 0; j < 5; ++j) cw[i][j] = ((const f4a4*)crow)[j];
        c20[i] = crow[20];
        gg[i] = crow[ct[i]];
    }
    int myp = 0, myn = 0;
    #pragma unroll
    for (int i = 0; i < 3; ++i) {
        float m = c20[i];
        #pragma unroll
        for (int j = 0; j < 5; ++j)
            m = fmaxf(m, fmaxf(fmaxf(cw[i][j].x, cw[i][j].y), fmaxf(cw[i][j].z, cw[i][j].w)));
        float sum = __expf(c20[i] - m);
        #pragma unroll
        for (int j = 0; j < 5; ++j)
            sum += __expf(cw[i][j].x - m) + __expf(cw[i][j].y - m)
                 + __expf(cw[i][j].z - m) + __expf(cw[i][j].w - m);
        const float ce = m + __logf(sum) - gg[i];
        if (vld[i]) wsf[2u * (rb + pr[i])] = ce;
        const bool pos = ct[i] > 0;
        myp += (vld[i] && pos) ? 1 : 0;
        myn += (vld[i] && !pos && f2k(ce) != 0x80000000u) ? 1 : 0;
    }
    double v;
    v = blockReduce((double)myp, sred);
    if (tid == 0) partPN[0 * GBLK + blockIdx.x] = v;   // pos count
    v = blockReduce((double)myn, sred);
    if (tid == 0) partPN[1 * GBLK + blockIdx.x] = v;   // nonzero-key negative count
}

// B: smooth-L1 partials + has_lp CE/posbit -> ws_ch.y; partL[0..2]. (r8-verified.)
__global__ __launch_bounds__(256, 4) void k_sl1(
    const float* __restrict__ loc_data, const float* __restrict__ has_lp_data,
    const float* __restrict__ size_lp_data, const float* __restrict__ offset_data,
    const float* __restrict__ loc_t, const int* __restrict__ conf_t,
    const int* __restrict__ has_lp_t, const float* __restrict__ size_lp_t,
    const float* __restrict__ offset_t,
    float* __restrict__ wsf /* = (float*)ws_ch */, double* __restrict__ partL)
{
    __shared__ double sred[4];
    const int tid = threadIdx.x;
    const int b = blockIdx.x >> 5, s = blockIdx.x & 31;

    int pr[3]; bool vld[3];
    #pragma unroll
    for (int i = 0; i < 3; ++i) {
        int p = s * SLABR + i * 256 + tid;
        vld[i] = p < PRI;
        pr[i] = vld[i] ? p : PRI - 1;
    }
    const unsigned rb = (unsigned)b * PRI;

    int ct[3], hl[3]; float4 lp[3], lt[3]; float2 sp2[3], st2[3], op2[3], ot2[3], hh[3];
    #pragma unroll
    for (int i = 0; i < 3; ++i) {
        const unsigned r = rb + pr[i];
        ct[i] = conf_t[r];
        hl[i] = has_lp_t[r];
        lp[i] = ((const float4*)loc_data)[r];
        lt[i] = ((const float4*)loc_t)[r];
        sp2[i] = ((const float2*)size_lp_data)[r];
        st2[i] = ((const float2*)size_lp_t)[r];
        op2[i] = ((const float2*)offset_data)[r];
        ot2[i] = ((const float2*)offset_t)[r];
        hh[i] = ((const float2*)has_lp_data)[r];
    }
    double aL = 0.0, aS = 0.0, aO = 0.0;
    #pragma unroll
    for (int i = 0; i < 3; ++i) {
        const bool pos = ct[i] > 0;
        float ll = sl1f(lp[i].x, lt[i].x) + sl1f(lp[i].y, lt[i].y)
                 + sl1f(lp[i].z, lt[i].z) + sl1f(lp[i].w, lt[i].w);
        float ls = sl1f(sp2[i].x, st2[i].x) + sl1f(sp2[i].y, st2[i].y);
        float lo = sl1f(op2[i].x, ot2[i].x) + sl1f(op2[i].y, ot2[i].y);
        const float pf = (vld[i] && pos) ? 1.f : 0.f;
        const float hf = (hl[i] != 0) ? 1.f : 0.f;
        aL += (double)(pf * ll);
        aS += (double)(pf * hf * ls);
        aO += (double)(pf * hf * lo);
        float hm = fmaxf(hh[i].x, hh[i].y);
        float hs = __expf(hh[i].x - hm) + __expf(hh[i].y - hm);
        float hlce = fmaxf(hm + __logf(hs) - (hl[i] != 0 ? hh[i].y : hh[i].x), 0.0f);
        unsigned hb = __float_as_uint(hlce) | (pos ? 0x80000000u : 0u);
        if (vld[i]) wsf[2u * (rb + pr[i]) + 1u] = __uint_as_float(hb);
    }
    double v;
    v = blockReduce(aL, sred); if (tid == 0) partL[0 * GBLK + blockIdx.x] = v;
    v = blockReduce(aS, sred); if (tid == 0) partL[1 * GBLK + blockIdx.x] = v;
    v = blockReduce(aO, sred); if (tid == 0) partL[2 * GBLK + blockIdx.x] = v;
}

// Threshold decision per batch (64 tiny blocks). Common path (K>M on this data):
// reads 64 doubles, writes T/need — ~2 us. Radix fallback kept correct (dead here).
__global__ __launch_bounds__(256) void k_thr(
    const float2* __restrict__ ws_ch, const double* __restrict__ partPN,
    unsigned* __restrict__ selT, int* __restrict__ needed)
{
    const int b = blockIdx.x, tid = threadIdx.x;
    __shared__ double sred[4];
    __shared__ int shist[4096];
    __shared__ int sct[256];
    __shared__ unsigned s_dig;
    __shared__ int s_rem;
    __shared__ int s_K, s_M;

    double np = blockReduce((tid < SLABS) ? partPN[0 * GBLK + b * SLABS + tid] : 0.0, sred);
    double mm = blockReduce((tid < SLABS) ? partPN[1 * GBLK + b * SLABS + tid] : 0.0, sred);
    if (tid == 0) {
        int K = 3 * (int)(np + 0.5); if (K > PRI - 1) K = PRI - 1;
        s_K = K; s_M = (int)(mm + 0.5);
    }
    __syncthreads();
    const int K = s_K, M = s_M;

    if (K <= 0) { if (tid == 0) { selT[b] = SENT; needed[b] = 0; } return; }
    if (K > M)  { if (tid == 0) { selT[b] = 0x80000000u; needed[b] = K - M; } return; }

    // ---- rare path: 3-round LDS radix on CE keys (never taken on this data) ----
    const float2* row = ws_ch + (unsigned)b * PRI;
    for (int k = tid; k < 4096; k += 256) shist[k] = 0;
    __syncthreads();
    for (int p = tid; p < PRI; p += 256) {
        unsigned key = chkey(row[p]);
        if (key != 0x80000000u) atomicAdd(&shist[key >> 20], 1);
    }
    __syncthreads();
    {
        int h[16]; int ctn = 0;
        #pragma unroll
        for (int j = 0; j < 16; ++j) { h[j] = shist[tid * 16 + j]; ctn += h[j]; }
        sct[tid] = ctn;
        __syncthreads();
        #pragma unroll
        for (int off = 1; off < 256; off <<= 1) {   // suffix sum
            int v = (tid + off < 256) ? sct[tid + off] : 0;
            __syncthreads();
            sct[tid] += v;
            __syncthreads();
        }
        const int Sa = (tid < 255) ? sct[tid + 1] : 0;
        int cum = Sa;
        #pragma unroll
        for (int j = 15; j >= 0; --j) {
            int c2 = cum + h[j];
            if (c2 >= K && cum < K) { s_dig = (unsigned)(tid * 16 + j); s_rem = K - cum; }
            cum = c2;
        }
        __syncthreads();
    }
    unsigned pref = s_dig; int rem = s_rem;
    __syncthreads();

    // refine 1: 1024 bins on bits 19..10 where key>>20 == pref
    for (int k = tid; k < 1024; k += 256) shist[k] = 0;
    __syncthreads();
    for (int p = tid; p < PRI; p += 256) {
        unsigned key = chkey(row[p]);
        if (key != 0x80000000u && (key >> 20) == pref)
            atomicAdd(&shist[(key >> 10) & 1023], 1);
    }
    __syncthreads();
    {
        int h4[4]; int c4 = 0;
        #pragma unroll
        for (int j = 0; j < 4; ++j) { h4[j] = shist[tid * 4 + j]; c4 += h4[j]; }
        sct[tid] = c4;
        __syncthreads();
        #pragma unroll
        for (int off = 1; off < 256; off <<= 1) {
            int v = (tid + off < 256) ? sct[tid + off] : 0;
            __syncthreads();
            sct[tid] += v;
            __syncthreads();
        }
        const int Sa = (tid < 255) ? sct[tid + 1] : 0;
        int cum = Sa;
        #pragma unroll
        for (int j = 3; j >= 0; --j) {
            int c2 = cum + h4[j];
            if (c2 >= rem && cum < rem) { s_dig = (unsigned)(tid * 4 + j); s_rem = rem - cum; }
            cum = c2;
        }
        __syncthreads();
    }
    pref = (pref << 10) | s_dig; rem = s_rem;
    __syncthreads();

    // refine 2: low 10 bits where key>>10 == pref
    for (int k = tid; k < 1024; k += 256) shist[k] = 0;
    __syncthreads();
    for (int p = tid; p < PRI; p += 256) {
        unsigned key = chkey(row[p]);
        if (key != 0x80000000u && (key >> 10) == pref)
            atomicAdd(&shist[key & 1023], 1);
    }
    __syncthreads();
    {
        int h4[4]; int c4 = 0;
        #pragma unroll
        for (int j = 0; j < 4; ++j) { h4[j] = shist[tid * 4 + j]; c4 += h4[j]; }
        sct[tid] = c4;
        __syncthreads();
        #pragma unroll
        for (int off = 1; off < 256; off <<= 1) {
            int v = (tid + off < 256) ? sct[tid + off] : 0;
            __syncthreads();
            sct[tid] += v;
            __syncthreads();
        }
        const int Sa = (tid < 255) ? sct[tid + 1] : 0;
        int cum = Sa;
        #pragma unroll
        for (int j = 3; j >= 0; --j) {
            int c2 = cum + h4[j];
            if (c2 >= rem && cum < rem) { s_dig = (unsigned)(tid * 4 + j); s_rem = rem - cum; }
            cum = c2;
        }
        __syncthreads();
    }
    if (tid == 0) { selT[b] = (pref << 10) | s_dig; needed[b] = s_rem; }
}

// Per-slab: tie count (key==T) + selected-core sums (pos || key>T) + tie-negative
// sums. 2048 blocks — full-GPU parallel. (r1-verified body.)
__global__ __launch_bounds__(256) void k_sel2(
    const float2* __restrict__ ws_ch, const unsigned* __restrict__ selT,
    int* __restrict__ cntT, double* __restrict__ sums)
{
    __shared__ double sred[4];
    const int tid = threadIdx.x;
    const int b = blockIdx.x >> 5, s = blockIdx.x & 31;
    const unsigned T = selT[b];
    double aC = 0.0, aH = 0.0, tC = 0.0, tH = 0.0, cc = 0.0;
    #pragma unroll
    for (int i = 0; i < 3; ++i) {
        const int p = s * SLABR + i * 256 + tid;
        if (p < PRI) {
            float2 ch = ws_ch[(unsigned)b * PRI + p];
            unsigned hb = __float_as_uint(ch.y);
            const bool pos = (hb >> 31) != 0;
            const unsigned key = pos ? 0x80000000u : f2k(ch.x);
            const float hlv = __uint_as_float(hb & 0x7fffffffu);
            if (pos || key > T) { aC += (double)ch.x; aH += (double)hlv; }
            if (key == T) {
                cc += 1.0;
                if (!pos) { tC += (double)ch.x; tH += (double)hlv; }
            }
        }
    }
    double v;
    v = blockReduce(aC, sred); if (tid == 0) sums[0 * GBLK + blockIdx.x] = v;
    v = blockReduce(aH, sred); if (tid == 0) sums[1 * GBLK + blockIdx.x] = v;
    v = blockReduce(tC, sred); if (tid == 0) sums[2 * GBLK + blockIdx.x] = v;
    v = blockReduce(tH, sred); if (tid == 0) sums[3 * GBLK + blockIdx.x] = v;
    v = blockReduce(cc, sred); if (tid == 0) cntT[blockIdx.x] = (int)(v + 0.5);
}

// Per batch: find cutoff slab from tie counts, scan it for the needed-th tie,
// add tie-negative partials, emit (loss_c, loss_has_lp). (r1-verified body.)
__global__ __launch_bounds__(256) void k_cut(
    const float2* __restrict__ ws_ch, const unsigned* __restrict__ selT,
    const int* __restrict__ needed, const int* __restrict__ cntT,
    const double* __restrict__ sums, double* __restrict__ lossCH)
{
    const int b = blockIdx.x, tid = threadIdx.x;
    __shared__ double sred[4];
    __shared__ int scnt_s[32];
    __shared__ int s_sl, s_loc, s_found;
    __shared__ int wtot[4];
    const int need = needed[b];
    const unsigned T = selT[b];

    if (tid < 32) scnt_s[tid] = cntT[b * 32 + tid];
    __syncthreads();
    if (tid == 0) {
        int sl = 32, loc = 0, cum = 0;
        if (need > 0) {
            for (int s2 = 0; s2 < 32; ++s2) {
                int c2 = scnt_s[s2];
                if (cum + c2 >= need) { sl = s2; loc = need - cum; break; }
                cum += c2;
            }
        }
        s_sl = sl; s_loc = loc; s_found = -1;
    }
    __syncthreads();
    const int sl = s_sl, loc = s_loc;

    // base: all selected-core sums + tie-neg sums for slabs fully before sl
    double aC = 0.0, aH = 0.0;
    if (tid < 32) {
        aC = sums[0 * GBLK + b * 32 + tid] + (tid < sl ? sums[2 * GBLK + b * 32 + tid] : 0.0);
        aH = sums[1 * GBLK + b * 32 + tid] + (tid < sl ? sums[3 * GBLK + b * 32 + tid] : 0.0);
    }
    double totC = blockReduce(aC, sred);
    double totH = blockReduce(aH, sred);

    if (sl < 32) {
        // pass 1: find cutoff = global index of the loc-th key==T row in slab sl
        int run = 0;
        for (int i = 0; i < 3; ++i) {
            const int p = sl * SLABR + i * 256 + tid;
            bool eq = false;
            if (p < PRI) eq = (chkey(ws_ch[(unsigned)b * PRI + p]) == T);
            const unsigned long long m = __ballot(eq);
            const int lane = tid & 63, wid = tid >> 6;
            if (lane == 0) wtot[wid] = __popcll(m);
            const int mex = __popcll(m & ((1ull << lane) - 1ull));
            __syncthreads();
            int woff = 0;
            for (int w = 0; w < wid; ++w) woff += wtot[w];
            if (eq && (run + woff + mex + 1 == loc)) s_found = p;
            __syncthreads();
            run += wtot[0] + wtot[1] + wtot[2] + wtot[3];
            __syncthreads();
        }
        const int cutoff = s_found;
        // pass 2: tie-negative sums within slab sl with p <= cutoff
        double pC = 0.0, pH = 0.0;
        for (int i = 0; i < 3; ++i) {
            const int p = sl * SLABR + i * 256 + tid;
            if (p < PRI && p <= cutoff) {
                float2 ch = ws_ch[(unsigned)b * PRI + p];
                unsigned hb = __float_as_uint(ch.y);
                const bool pos = (hb >> 31) != 0;
                const unsigned key = pos ? 0x80000000u : f2k(ch.x);
                if (!pos && key == T) {
                    pC += (double)ch.x;
                    pH += (double)__uint_as_float(hb & 0x7fffffffu);
                }
            }
        }
        double v1 = blockReduce(pC, sred);
        double v2 = blockReduce(pH, sred);
        if (tid == 0) { totC += v1; totH += v2; }
    }
    if (tid == 0) { lossCH[b] = totC; lossCH[64 + b] = totH; }
}

// Sum partials, divide by N, emit 5 outputs.
__global__ __launch_bounds__(256) void k_final(
    const double* __restrict__ partL, const double* __restrict__ partPN,
    const double* __restrict__ lossCH, float* __restrict__ out)
{
    __shared__ double sred[4];
    const int tid = threadIdx.x;
    double s[3];
    #pragma unroll
    for (int k = 0; k < 3; ++k) {
        double a = 0.0;
        for (int t = tid; t < GBLK; t += 256) a += partL[k * GBLK + t];
        s[k] = blockReduce(a, sred);
    }
    double a = 0.0;
    for (int t = tid; t < GBLK; t += 256) a += partPN[t];
    double n = blockReduce(a, sred);
    double lc = (tid < BATCH) ? lossCH[tid] : 0.0;
    lc = blockReduce(lc, sred);
    double lh = (tid < BATCH) ? lossCH[64 + tid] : 0.0;
    lh = blockReduce(lh, sred);
    if (tid == 0) {
        out[0] = (float)(s[0] / n);   // loss_l
        out[1] = (float)(lc / n);     // loss_c
        out[2] = (float)(s[1] / n);   // loss_size_lp
        out[3] = (float)(s[2] / n);   // loss_offset
        out[4] = (float)(lh / n);     // loss_has_lp
    }
}

extern "C" void kernel_launch(void* const* d_in, const int* in_sizes, int n_in,
                              void* d_out, int out_size, void* d_ws, size_t ws_size,
                              hipStream_t stream)
{
    const float* loc_data     = (const float*)d_in[0];
    const float* conf_data    = (const float*)d_in[1];
    const float* has_lp_data  = (const float*)d_in[2];
    const float* size_lp_data = (const float*)d_in[3];
    const float* offset_data  = (const float*)d_in[4];
    const float* loc_t        = (const float*)d_in[5];
    const int*   conf_t       = (const int*)d_in[6];
    const int*   has_lp_t     = (const int*)d_in[7];
    const float* size_lp_t    = (const float*)d_in[8];
    const float* offset_t     = (const float*)d_in[9];
    float* out = (float*)d_out;

    char* ws = (char*)d_ws;
    unsigned* selT   = (unsigned*)(ws + 0);      // 64 u32
    int* needed      = (int*)(ws + 512);         // 64 int
    int* cntT        = (int*)(ws + 1536);        // 2048 int (8 KB)
    double* partL    = (double*)(ws + 16384);    // 3*2048 doubles (48 KB)
    double* partPN   = (double*)(ws + 65536);    // 2*2048 doubles (32 KB)
    double* sums     = (double*)(ws + 131072);   // 4*2048 doubles (64 KB)
    double* lossCH   = (double*)(ws + 262144);   // 128 doubles
    float2* ws_ch    = (float2*)(ws + 1704960);  // NROWS float2 (~12.6 MB)
    float*  wsf      = (float*)ws_ch;

    // No memsets: every workspace word consumed is written unconditionally
    // by an earlier kernel in the same graph.
    k_ce<<<GBLK, 256, 0, stream>>>(conf_data, conf_t, wsf, partPN);
    k_sl1<<<GBLK, 256, 0, stream>>>(loc_data, has_lp_data, size_lp_data, offset_data,
                                    loc_t, conf_t, has_lp_t, size_lp_t, offset_t,
                                    wsf, partL);
    k_thr<<<BATCH, 256, 0, stream>>>(ws_ch, partPN, selT, needed);
    k_sel2<<<GBLK, 256, 0, stream>>>(ws_ch, selT, cntT, sums);
    k_cut<<<BATCH, 256, 0, stream>>>(ws_ch, selT, needed, cntT, sums, lossCH);
    k_final<<<1, 256, 0, stream>>>(partL, partPN, lossCH, out);
}